// Round 16
// baseline (223.812 us; speedup 1.0000x reference)
//
#include <hip/hip_runtime.h>
#include <hip/hip_bf16.h>

typedef unsigned long long u64;
typedef unsigned int u32;
typedef unsigned short ushort8 __attribute__((ext_vector_type(8)));
typedef unsigned short ushortx16 __attribute__((ext_vector_type(16)));
typedef u64 u64x4 __attribute__((ext_vector_type(4)));
typedef float fx4 __attribute__((ext_vector_type(4)));

#define IMG_H 256
#define IMG_W 256
#define CIN   64
#define HW    (IMG_H * IMG_W)   // 65536
#define NPIX  (8 * HW)          // 524288

static __device__ __forceinline__ float bf16bits_to_f32(unsigned short h) {
    union { u32 u; float f; } c;
    c.u = ((u32)h) << 16;
    return c.f;
}
static __device__ __forceinline__ unsigned short f32_to_bf16bits(float f) {
    __hip_bfloat16 hb = __float2bfloat16(f);
    return *(unsigned short*)&hb;
}

// ---------------------------------------------------------------------------
// Kernel P: pack weight sign bits + per-out-channel alpha = mean(|w|).
// ---------------------------------------------------------------------------
__global__ void prep_kernel(const float* __restrict__ w1,
                            const float* __restrict__ w2,
                            u64* __restrict__ w1b, float* __restrict__ a1,
                            u64* __restrict__ w2b, float* __restrict__ a2) {
    int blk = blockIdx.x;
    int lane = threadIdx.x;  // 0..63
    const float* w;
    u64* wb;
    float* al;
    if (blk < 64) { w = w1 + (size_t)blk * 576;        wb = w1b + blk * 9;        al = a1 + blk; }
    else          { w = w2 + (size_t)(blk - 64) * 576; wb = w2b + (blk - 64) * 9; al = a2 + (blk - 64); }

    const float* wi = w + lane * 9;
    float s = 0.f;
    u64 bits[9];
#pragma unroll
    for (int t = 0; t < 9; ++t) {
        float v = wi[t];
        s += fabsf(v);
        bits[t] = __ballot(v > 0.f);
    }
#pragma unroll
    for (int m = 32; m >= 1; m >>= 1) s += __shfl_xor(s, m);
    if (lane == 0) {
        *al = s * (1.f / 576.f);
#pragma unroll
        for (int t = 0; t < 9; ++t) wb[t] = bits[t];
    }
}

// ---------------------------------------------------------------------------
// Kernel 1: pack sign(x + b_in). 4 px/thread, fx4 loads, u32 bit accum.
// ---------------------------------------------------------------------------
__global__ __launch_bounds__(256)
void pack_kernel(const float* __restrict__ x,
                 const float* __restrict__ b_in,
                 u64* __restrict__ bits1) {
    int tid = blockIdx.x * 256 + threadIdx.x;     // over NPIX/4
    int n = tid >> 14;
    int p = (tid & 16383) * 4;
    const float* xp = x + (size_t)n * CIN * HW + p;
    u32 lo[4] = {0, 0, 0, 0}, hi[4] = {0, 0, 0, 0};
#pragma unroll
    for (int c = 0; c < 32; ++c) {
        fx4 v = *(const fx4*)(xp + (size_t)c * HW);
        float b = b_in[c];
#pragma unroll
        for (int q = 0; q < 4; ++q) lo[q] |= (u32)((v[q] + b) > 0.f) << c;
    }
#pragma unroll
    for (int c = 0; c < 32; ++c) {
        fx4 v = *(const fx4*)(xp + (size_t)(c + 32) * HW);
        float b = b_in[c + 32];
#pragma unroll
        for (int q = 0; q < 4; ++q) hi[q] |= (u32)((v[q] + b) > 0.f) << c;
    }
    u64x4 pk;
#pragma unroll
    for (int q = 0; q < 4; ++q) pk[q] = ((u64)hi[q] << 32) | lo[q];
    *(u64x4*)(bits1 + (size_t)n * HW + p) = pk;
}

// ---------------------------------------------------------------------------
// Kernel 2: conv1 (binary popcount from bits1) + residual. 1 px/thread,
// A/B software pipeline, NT stores (champion r14 structure, unchanged).
// ---------------------------------------------------------------------------
__global__ __launch_bounds__(256)
void conv1_kernel(const float* __restrict__ x,
                  const float* __restrict__ b2_,
                  const u64* __restrict__ bits1,
                  const u64* __restrict__ wbits,
                  const float* __restrict__ alpha1,
                  ushort8* __restrict__ xres,
                  u64* __restrict__ bits2) {
    int i = blockIdx.x * 256 + threadIdx.x;
    int n = i >> 16, p = i & 65535;
    int y = p >> 8, xc = p & 255;

    u64 xb[9];
    int invmask = 0, nv = 0;
#pragma unroll
    for (int t = 0; t < 9; ++t) {
        int dy = t / 3 - 1, dx = t % 3 - 1;
        bool v = ((unsigned)(y + dy) < (unsigned)IMG_H) &
                 ((unsigned)(xc + dx) < (unsigned)IMG_W);
        xb[t] = v ? bits1[i + dy * IMG_W + dx] : 0ull;
        invmask |= (v ? 0 : 1) << t;
        nv += v ? 1 : 0;
    }

    const float* xp = x + (size_t)n * CIN * HW + p;
    u64 w2 = 0;

    float rvA[8], rvB[8];

    auto load_rv = [&](float* buf, int g) {
#pragma unroll
        for (int j = 0; j < 8; ++j)
            buf[j] = xp[(size_t)(g * 8 + j) * HW];
    };
    auto comp = [&](const float* buf, int g) {
        ushort8 pk;
        u32 gm = 0;
#pragma unroll
        for (int j = 0; j < 8; ++j) {
            int o = g * 8 + j;
            const u64* wo = wbits + o * 9;
            int D = 0;
#pragma unroll
            for (int t = 0; t < 9; ++t) D += __popcll(xb[t] ^ wo[t]);
            int S = 64 * nv - 2 * D;
            if (invmask) {
#pragma unroll
                for (int t = 0; t < 9; ++t)
                    if ((invmask >> t) & 1) S += 2 * __popcll(wo[t]);
            }
            float r = alpha1[o] * (float)S + buf[j];
            pk[j] = f32_to_bf16bits(r);
            gm |= (u32)((r + b2_[o]) > 0.f) << j;
        }
        __builtin_nontemporal_store(pk, xres + (size_t)(n * 8 + g) * HW + p);
        w2 |= (u64)gm << (8 * g);
    };

    load_rv(rvA, 0);
#pragma unroll 1
    for (int gg = 0; gg < 4; ++gg) {
        load_rv(rvB, 2 * gg + 1);
        comp(rvA, 2 * gg);
        if (gg < 3) load_rv(rvA, 2 * gg + 2);
        comp(rvB, 2 * gg + 1);
    }
    __builtin_nontemporal_store(w2, bits2 + i);
}

// ---------------------------------------------------------------------------
// Kernel 3: conv2 + shortcut + b3 + PReLU(s2) + b4 + fused pixel_shuffle(2).
// 4 px/thread (horizontal quad): W[3][6] shared tap window, 64B xres visits
// (2x ushortx16, A/B pipelined), 2x fx4 NT stores per (co,r1) = 32B/thread,
// 2KB contiguous per wave-store. Write-dominated kernel: trades occupancy
// (which writes don't need - fillBuffer: 7TB/s @ 10%) for burst length.
// ---------------------------------------------------------------------------
__global__ __launch_bounds__(256)
void conv2_kernel(const ushort8* __restrict__ xres,
                  const u64* __restrict__ bits2,
                  const u64* __restrict__ wbits,
                  const float* __restrict__ alpha2,
                  const float* __restrict__ b3,
                  const float* __restrict__ s2,
                  const float* __restrict__ b4,
                  float* __restrict__ out) {
    int tid = blockIdx.x * 256 + threadIdx.x;   // over NPIX/4
    int n = tid >> 14;
    int p = (tid & 16383) * 4;
    int y = p >> 8, xc = p & 255;   // xc multiple of 4

    u64 W[3][6];
    const u64* bp = bits2 + (size_t)n * HW;
#pragma unroll
    for (int r = 0; r < 3; ++r) {
        int yy = y - 1 + r;
        bool rv = (unsigned)yy < (unsigned)IMG_H;
        const u64* row = bp + yy * IMG_W + xc;
        W[r][0] = (rv && xc > 0)   ? row[-1] : 0ull;
        W[r][1] = rv ? row[0] : 0ull;
        W[r][2] = rv ? row[1] : 0ull;
        W[r][3] = rv ? row[2] : 0ull;
        W[r][4] = rv ? row[3] : 0ull;
        W[r][5] = (rv && xc < 252) ? row[4] : 0ull;
    }
    // validity per pixel q (col xc+q); only q=0 (left) / q=3 (right) can hit x-edges
    int inv[4], nv[4];
#pragma unroll
    for (int q = 0; q < 4; ++q) { inv[q] = 0; nv[q] = 0; }
#pragma unroll
    for (int t = 0; t < 9; ++t) {
        const int r = t / 3, c = t % 3;
        bool rowv = (unsigned)(y - 1 + r) < (unsigned)IMG_H;
#pragma unroll
        for (int q = 0; q < 4; ++q) {
            bool v = rowv && ((unsigned)(xc + q - 1 + c) < (unsigned)IMG_W);
            inv[q] |= (v ? 0 : 1) << t;
            nv[q] += v ? 1 : 0;
        }
    }
    const int edge = inv[0] | inv[3];   // inv[1],inv[2] only have row bits, subset of inv[0]

    const ushortx16* xrp = (const ushortx16*)(xres + (size_t)n * 8 * HW + p);
    float* ob = out + (size_t)n * 32 * 512 * 512;
    const int Y = 2 * y, X = 2 * xc;

    auto comp = [&](const ushortx16& x01, const ushortx16& x23, int g) {
#pragma unroll
        for (int jj = 0; jj < 8; jj += 2) {
            float lo[4][2], hi[4][2];
#pragma unroll
            for (int q2 = 0; q2 < 2; ++q2) {
                int o = g * 8 + jj + q2;
                float xrv[4];
                xrv[0] = bf16bits_to_f32(x01[jj + q2]);
                xrv[1] = bf16bits_to_f32(x01[8 + jj + q2]);
                xrv[2] = bf16bits_to_f32(x23[jj + q2]);
                xrv[3] = bf16bits_to_f32(x23[8 + jj + q2]);
                // low channel o
                {
                    const u64* wo = wbits + o * 9;
                    int D[4] = {0, 0, 0, 0};
#pragma unroll
                    for (int t = 0; t < 9; ++t) {
                        const int r = t / 3, c = t % 3;
                        u64 w = wo[t];
#pragma unroll
                        for (int q = 0; q < 4; ++q)
                            D[q] += __popcll(W[r][c + q] ^ w);
                    }
                    float ka = 1.25f * alpha2[o], bb = b3[o], ss = s2[o], b4v = b4[o];
#pragma unroll
                    for (int q = 0; q < 4; ++q) {
                        int S = 64 * nv[q] - 2 * D[q];
                        if (edge && inv[q]) {
#pragma unroll
                            for (int t = 0; t < 9; ++t)
                                if ((inv[q] >> t) & 1) S += 2 * __popcll(wo[t]);
                        }
                        float u = ka * (float)S + xrv[q] + bb;
                        u = (u >= 0.f) ? u : ss * u;
                        lo[q][q2] = u + b4v;
                    }
                }
                // high channel o + 64
                {
                    int o2 = o + 64;
                    const u64* wo = wbits + o2 * 9;
                    int D[4] = {0, 0, 0, 0};
#pragma unroll
                    for (int t = 0; t < 9; ++t) {
                        const int r = t / 3, c = t % 3;
                        u64 w = wo[t];
#pragma unroll
                        for (int q = 0; q < 4; ++q)
                            D[q] += __popcll(W[r][c + q] ^ w);
                    }
                    float ka = 1.25f * alpha2[o2], bb = b3[o2], ss = s2[o2], b4v = b4[o2];
#pragma unroll
                    for (int q = 0; q < 4; ++q) {
                        int S = 64 * nv[q] - 2 * D[q];
                        if (edge && inv[q]) {
#pragma unroll
                            for (int t = 0; t < 9; ++t)
                                if ((inv[q] >> t) & 1) S += 2 * __popcll(wo[t]);
                        }
                        float u = ka * (float)S + xrv[q] + bb;
                        u = (u >= 0.f) ? u : ss * u;
                        hi[q][q2] = u + b4v;
                    }
                }
            }
            // o = co*4 + r1*2 + r2; px q, ch (o,o+1) -> cols X+2q, X+2q+1
            int o = g * 8 + jj;
            int co = o >> 2;
            int r1 = (o >> 1) & 1;
            float* rowp = ob + ((size_t)co * 512 + Y + r1) * 512 + X;
            float* rowp2 = ob + ((size_t)(co + 16) * 512 + Y + r1) * 512 + X;
            fx4 v0; v0.x = lo[0][0]; v0.y = lo[0][1]; v0.z = lo[1][0]; v0.w = lo[1][1];
            fx4 v1; v1.x = lo[2][0]; v1.y = lo[2][1]; v1.z = lo[3][0]; v1.w = lo[3][1];
            fx4 h0; h0.x = hi[0][0]; h0.y = hi[0][1]; h0.z = hi[1][0]; h0.w = hi[1][1];
            fx4 h1; h1.x = hi[2][0]; h1.y = hi[2][1]; h1.z = hi[3][0]; h1.w = hi[3][1];
            __builtin_nontemporal_store(v0, (fx4*)rowp);
            __builtin_nontemporal_store(v1, (fx4*)(rowp + 4));
            __builtin_nontemporal_store(h0, (fx4*)rowp2);
            __builtin_nontemporal_store(h1, (fx4*)(rowp2 + 4));
        }
    };

    // A/B pipelined xres loads: 2x ushortx16 (64B) per group
    ushortx16 a0 = __builtin_nontemporal_load(xrp);
    ushortx16 a1 = __builtin_nontemporal_load(xrp + 1);
#pragma unroll 1
    for (int gg = 0; gg < 4; ++gg) {
        size_t ob1 = (size_t)(2 * gg + 1) * (HW / 2);
        ushortx16 b0 = __builtin_nontemporal_load(xrp + ob1);
        ushortx16 b1 = __builtin_nontemporal_load(xrp + ob1 + 1);
        comp(a0, a1, 2 * gg);
        if (gg < 3) {
            size_t ob2 = (size_t)(2 * gg + 2) * (HW / 2);
            a0 = __builtin_nontemporal_load(xrp + ob2);
            a1 = __builtin_nontemporal_load(xrp + ob2 + 1);
        }
        comp(b0, b1, 2 * gg + 1);
    }
}

// ---------------------------------------------------------------------------
extern "C" void kernel_launch(void* const* d_in, const int* in_sizes, int n_in,
                              void* d_out, int out_size, void* d_ws, size_t ws_size,
                              hipStream_t stream) {
    const float* x    = (const float*)d_in[0];
    const float* w1   = (const float*)d_in[1];
    const float* w2   = (const float*)d_in[2];
    const float* b_in = (const float*)d_in[3];
    // d_in[4]=b1, d_in[5]=s1, d_in[6]=b2 are dead code in the reference
    const float* b2_  = (const float*)d_in[7];
    const float* b3   = (const float*)d_in[8];
    const float* s2   = (const float*)d_in[9];
    const float* b4   = (const float*)d_in[10];
    float* out = (float*)d_out;

    char* ws = (char*)d_ws;
    u64*   w1b   = (u64*)(ws + 0);                    // 4608 B
    u64*   w2b   = (u64*)(ws + 4608);                 // 9216 B
    float* a1    = (float*)(ws + 13824);              // 256 B
    float* a2    = (float*)(ws + 14080);              // 512 B
    u64*   bits1 = (u64*)(ws + 16384);                // 4 MiB
    u64*   bits2 = (u64*)(ws + 16384 + 4194304);      // 4 MiB
    ushort8* xres = (ushort8*)(ws + 16384 + 2 * 4194304);  // 64 MiB

    prep_kernel<<<192, 64, 0, stream>>>(w1, w2, w1b, a1, w2b, a2);

    pack_kernel <<<NPIX / 1024, 256, 0, stream>>>(x, b_in, bits1);
    conv1_kernel<<<NPIX / 256, 256, 0, stream>>>(x, b2_, bits1, w1b, a1, xres, bits2);
    conv2_kernel<<<NPIX / 1024, 256, 0, stream>>>(xres, bits2, w2b, a2, b3, s2, b4, out);
}

// Round 17
// 204.921 us; speedup vs baseline: 1.0922x; 1.0922x over previous
//
#include <hip/hip_runtime.h>
#include <hip/hip_bf16.h>

typedef unsigned long long u64;
typedef unsigned int u32;
typedef unsigned short ushort8 __attribute__((ext_vector_type(8)));
typedef unsigned short ushortx16 __attribute__((ext_vector_type(16)));
typedef u64 u64x2 __attribute__((ext_vector_type(2)));
typedef u64 u64x4 __attribute__((ext_vector_type(4)));
typedef float fx2 __attribute__((ext_vector_type(2)));
typedef float fx4 __attribute__((ext_vector_type(4)));

#define IMG_H 256
#define IMG_W 256
#define CIN   64
#define HW    (IMG_H * IMG_W)   // 65536
#define NPIX  (8 * HW)          // 524288

static __device__ __forceinline__ float bf16bits_to_f32(unsigned short h) {
    union { u32 u; float f; } c;
    c.u = ((u32)h) << 16;
    return c.f;
}
static __device__ __forceinline__ unsigned short f32_to_bf16bits(float f) {
    __hip_bfloat16 hb = __float2bfloat16(f);
    return *(unsigned short*)&hb;
}

// ---------------------------------------------------------------------------
// Kernel P: pack weight sign bits + per-out-channel alpha = mean(|w|).
// ---------------------------------------------------------------------------
__global__ void prep_kernel(const float* __restrict__ w1,
                            const float* __restrict__ w2,
                            u64* __restrict__ w1b, float* __restrict__ a1,
                            u64* __restrict__ w2b, float* __restrict__ a2) {
    int blk = blockIdx.x;
    int lane = threadIdx.x;  // 0..63
    const float* w;
    u64* wb;
    float* al;
    if (blk < 64) { w = w1 + (size_t)blk * 576;        wb = w1b + blk * 9;        al = a1 + blk; }
    else          { w = w2 + (size_t)(blk - 64) * 576; wb = w2b + (blk - 64) * 9; al = a2 + (blk - 64); }

    const float* wi = w + lane * 9;
    float s = 0.f;
    u64 bits[9];
#pragma unroll
    for (int t = 0; t < 9; ++t) {
        float v = wi[t];
        s += fabsf(v);
        bits[t] = __ballot(v > 0.f);
    }
#pragma unroll
    for (int m = 32; m >= 1; m >>= 1) s += __shfl_xor(s, m);
    if (lane == 0) {
        *al = s * (1.f / 576.f);
#pragma unroll
        for (int t = 0; t < 9; ++t) wb[t] = bits[t];
    }
}

// ---------------------------------------------------------------------------
// Kernel 1: pack sign(x + b_in). 4 px/thread, fx4 loads, u32 bit accum.
// ---------------------------------------------------------------------------
__global__ __launch_bounds__(256)
void pack_kernel(const float* __restrict__ x,
                 const float* __restrict__ b_in,
                 u64* __restrict__ bits1) {
    int tid = blockIdx.x * 256 + threadIdx.x;     // over NPIX/4
    int n = tid >> 14;
    int p = (tid & 16383) * 4;
    const float* xp = x + (size_t)n * CIN * HW + p;
    u32 lo[4] = {0, 0, 0, 0}, hi[4] = {0, 0, 0, 0};
#pragma unroll
    for (int c = 0; c < 32; ++c) {
        fx4 v = *(const fx4*)(xp + (size_t)c * HW);
        float b = b_in[c];
#pragma unroll
        for (int q = 0; q < 4; ++q) lo[q] |= (u32)((v[q] + b) > 0.f) << c;
    }
#pragma unroll
    for (int c = 0; c < 32; ++c) {
        fx4 v = *(const fx4*)(xp + (size_t)(c + 32) * HW);
        float b = b_in[c + 32];
#pragma unroll
        for (int q = 0; q < 4; ++q) hi[q] |= (u32)((v[q] + b) > 0.f) << c;
    }
    u64x4 pk;
#pragma unroll
    for (int q = 0; q < 4; ++q) pk[q] = ((u64)hi[q] << 32) | lo[q];
    *(u64x4*)(bits1 + (size_t)n * HW + p) = pk;
}

// ---------------------------------------------------------------------------
// Kernel 2: conv1 (binary popcount from bits1) + residual. 1 px/thread,
// A/B software pipeline. xres/bits2 written NON-TEMPORAL.
// ---------------------------------------------------------------------------
__global__ __launch_bounds__(256)
void conv1_kernel(const float* __restrict__ x,
                  const float* __restrict__ b2_,
                  const u64* __restrict__ bits1,
                  const u64* __restrict__ wbits,
                  const float* __restrict__ alpha1,
                  ushort8* __restrict__ xres,
                  u64* __restrict__ bits2) {
    int i = blockIdx.x * 256 + threadIdx.x;
    int n = i >> 16, p = i & 65535;
    int y = p >> 8, xc = p & 255;

    u64 xb[9];
    int invmask = 0, nv = 0;
#pragma unroll
    for (int t = 0; t < 9; ++t) {
        int dy = t / 3 - 1, dx = t % 3 - 1;
        bool v = ((unsigned)(y + dy) < (unsigned)IMG_H) &
                 ((unsigned)(xc + dx) < (unsigned)IMG_W);
        xb[t] = v ? bits1[i + dy * IMG_W + dx] : 0ull;
        invmask |= (v ? 0 : 1) << t;
        nv += v ? 1 : 0;
    }

    const float* xp = x + (size_t)n * CIN * HW + p;
    u64 w2 = 0;

    float rvA[8], rvB[8];

    auto load_rv = [&](float* buf, int g) {
#pragma unroll
        for (int j = 0; j < 8; ++j)
            buf[j] = xp[(size_t)(g * 8 + j) * HW];
    };
    auto comp = [&](const float* buf, int g) {
        ushort8 pk;
        u32 gm = 0;
#pragma unroll
        for (int j = 0; j < 8; ++j) {
            int o = g * 8 + j;
            const u64* wo = wbits + o * 9;
            int D = 0;
#pragma unroll
            for (int t = 0; t < 9; ++t) D += __popcll(xb[t] ^ wo[t]);
            int S = 64 * nv - 2 * D;
            if (invmask) {
#pragma unroll
                for (int t = 0; t < 9; ++t)
                    if ((invmask >> t) & 1) S += 2 * __popcll(wo[t]);
            }
            float r = alpha1[o] * (float)S + buf[j];
            pk[j] = f32_to_bf16bits(r);
            gm |= (u32)((r + b2_[o]) > 0.f) << j;
        }
        __builtin_nontemporal_store(pk, xres + (size_t)(n * 8 + g) * HW + p);
        w2 |= (u64)gm << (8 * g);
    };

    load_rv(rvA, 0);
#pragma unroll 1
    for (int gg = 0; gg < 4; ++gg) {
        load_rv(rvB, 2 * gg + 1);
        comp(rvA, 2 * gg);
        if (gg < 3) load_rv(rvA, 2 * gg + 2);
        comp(rvB, 2 * gg + 1);
    }
    __builtin_nontemporal_store(w2, bits2 + i);
}

// ---------------------------------------------------------------------------
// Kernel 3: conv2 + shortcut + b3 + PReLU(s2) + b4 + fused pixel_shuffle(2).
// 2 px/thread, fx4 NT stores, A/B pipelined NT xres loads.
// ---------------------------------------------------------------------------
__global__ __launch_bounds__(256)
void conv2_kernel(const ushort8* __restrict__ xres,
                  const u64* __restrict__ bits2,
                  const u64* __restrict__ wbits,
                  const float* __restrict__ alpha2,
                  const float* __restrict__ b3,
                  const float* __restrict__ s2,
                  const float* __restrict__ b4,
                  float* __restrict__ out) {
    int tid = blockIdx.x * 256 + threadIdx.x;   // over NPIX/2
    int n = tid >> 15;
    int p = (tid & 32767) * 2;
    int y = p >> 8, xc = p & 255;   // xc even

    u64 W[3][4];
    const u64* bp = bits2 + (size_t)n * HW;
#pragma unroll
    for (int r = 0; r < 3; ++r) {
        int yy = y - 1 + r;
        bool rv = (unsigned)yy < (unsigned)IMG_H;
        const u64* row = bp + yy * IMG_W + xc;
        W[r][0] = (rv && xc > 0)   ? row[-1] : 0ull;
        W[r][1] = rv ? row[0] : 0ull;
        W[r][2] = rv ? row[1] : 0ull;
        W[r][3] = (rv && xc < 254) ? row[2]  : 0ull;
    }
    int inv0 = 0, inv1 = 0, nv0 = 0, nv1 = 0;
#pragma unroll
    for (int t = 0; t < 9; ++t) {
        const int r = t / 3, c = t % 3;
        bool rv = (unsigned)(y - 1 + r) < (unsigned)IMG_H;
        bool v0 = rv && !(c == 0 && xc == 0);
        bool v1 = rv && !(c == 2 && xc == 254);
        inv0 |= (v0 ? 0 : 1) << t; nv0 += v0 ? 1 : 0;
        inv1 |= (v1 ? 0 : 1) << t; nv1 += v1 ? 1 : 0;
    }
    const int edge = inv0 | inv1;

    const ushortx16* xrp = (const ushortx16*)(xres + (size_t)n * 8 * HW + p);
    float* ob = out + (size_t)n * 32 * 512 * 512;
    const int Y = 2 * y, X = 2 * xc;

    ushortx16 xrA, xrB;

    auto comp = [&](const ushortx16& xr, int g) {
#pragma unroll
        for (int jj = 0; jj < 8; jj += 2) {
            float lo4[4], hi4[4];
#pragma unroll
            for (int q = 0; q < 2; ++q) {
                int o = g * 8 + jj + q;
                float xrv0 = bf16bits_to_f32(xr[jj + q]);       // px0
                float xrv1 = bf16bits_to_f32(xr[8 + jj + q]);   // px1
                // low channel o
                {
                    const u64* wo = wbits + o * 9;
                    int D0 = 0, D1 = 0;
#pragma unroll
                    for (int t = 0; t < 9; ++t) {
                        const int r = t / 3, c = t % 3;
                        u64 w = wo[t];
                        D0 += __popcll(W[r][c] ^ w);
                        D1 += __popcll(W[r][c + 1] ^ w);
                    }
                    int S0 = 64 * nv0 - 2 * D0;
                    int S1 = 64 * nv1 - 2 * D1;
                    if (edge) {
#pragma unroll
                        for (int t = 0; t < 9; ++t) {
                            int pw = __popcll(wo[t]);
                            if ((inv0 >> t) & 1) S0 += 2 * pw;
                            if ((inv1 >> t) & 1) S1 += 2 * pw;
                        }
                    }
                    float ka = 1.25f * alpha2[o], bb = b3[o], ss = s2[o], b4v = b4[o];
                    float u0 = ka * (float)S0 + xrv0 + bb;
                    float u1 = ka * (float)S1 + xrv1 + bb;
                    u0 = (u0 >= 0.f) ? u0 : ss * u0;
                    u1 = (u1 >= 0.f) ? u1 : ss * u1;
                    lo4[q] = u0 + b4v;
                    lo4[2 + q] = u1 + b4v;
                }
                // high channel o + 64
                {
                    int o2 = o + 64;
                    const u64* wo = wbits + o2 * 9;
                    int D0 = 0, D1 = 0;
#pragma unroll
                    for (int t = 0; t < 9; ++t) {
                        const int r = t / 3, c = t % 3;
                        u64 w = wo[t];
                        D0 += __popcll(W[r][c] ^ w);
                        D1 += __popcll(W[r][c + 1] ^ w);
                    }
                    int S0 = 64 * nv0 - 2 * D0;
                    int S1 = 64 * nv1 - 2 * D1;
                    if (edge) {
#pragma unroll
                        for (int t = 0; t < 9; ++t) {
                            int pw = __popcll(wo[t]);
                            if ((inv0 >> t) & 1) S0 += 2 * pw;
                            if ((inv1 >> t) & 1) S1 += 2 * pw;
                        }
                    }
                    float ka = 1.25f * alpha2[o2], bb = b3[o2], ss = s2[o2], b4v = b4[o2];
                    float u0 = ka * (float)S0 + xrv0 + bb;
                    float u1 = ka * (float)S1 + xrv1 + bb;
                    u0 = (u0 >= 0.f) ? u0 : ss * u0;
                    u1 = (u1 >= 0.f) ? u1 : ss * u1;
                    hi4[q] = u0 + b4v;
                    hi4[2 + q] = u1 + b4v;
                }
            }
            // o = co*4 + r1*2 + r2: (o,o+1) at px0 -> cols X,X+1; px1 -> X+2,X+3
            int o = g * 8 + jj;
            int co = o >> 2;
            int r1 = (o >> 1) & 1;
            fx4 vl; vl.x = lo4[0]; vl.y = lo4[1]; vl.z = lo4[2]; vl.w = lo4[3];
            fx4 vh; vh.x = hi4[0]; vh.y = hi4[1]; vh.z = hi4[2]; vh.w = hi4[3];
            __builtin_nontemporal_store(
                vl, (fx4*)(ob + ((size_t)co * 512 + Y + r1) * 512 + X));
            __builtin_nontemporal_store(
                vh, (fx4*)(ob + ((size_t)(co + 16) * 512 + Y + r1) * 512 + X));
        }
    };

    xrA = __builtin_nontemporal_load(xrp);
#pragma unroll 1
    for (int gg = 0; gg < 4; ++gg) {
        xrB = __builtin_nontemporal_load(xrp + (size_t)(2 * gg + 1) * (HW / 2));
        comp(xrA, 2 * gg);
        if (gg < 3) xrA = __builtin_nontemporal_load(xrp + (size_t)(2 * gg + 2) * (HW / 2));
        comp(xrB, 2 * gg + 1);
    }
}

// ---------------------------------------------------------------------------
extern "C" void kernel_launch(void* const* d_in, const int* in_sizes, int n_in,
                              void* d_out, int out_size, void* d_ws, size_t ws_size,
                              hipStream_t stream) {
    const float* x    = (const float*)d_in[0];
    const float* w1   = (const float*)d_in[1];
    const float* w2   = (const float*)d_in[2];
    const float* b_in = (const float*)d_in[3];
    // d_in[4]=b1, d_in[5]=s1, d_in[6]=b2 are dead code in the reference
    const float* b2_  = (const float*)d_in[7];
    const float* b3   = (const float*)d_in[8];
    const float* s2   = (const float*)d_in[9];
    const float* b4   = (const float*)d_in[10];
    float* out = (float*)d_out;

    char* ws = (char*)d_ws;
    u64*   w1b   = (u64*)(ws + 0);                    // 4608 B
    u64*   w2b   = (u64*)(ws + 4608);                 // 9216 B
    float* a1    = (float*)(ws + 13824);              // 256 B
    float* a2    = (float*)(ws + 14080);              // 512 B
    u64*   bits1 = (u64*)(ws + 16384);                // 4 MiB
    u64*   bits2 = (u64*)(ws + 16384 + 4194304);      // 4 MiB
    ushort8* xres = (ushort8*)(ws + 16384 + 2 * 4194304);  // 64 MiB

    prep_kernel<<<192, 64, 0, stream>>>(w1, w2, w1b, a1, w2b, a2);

    pack_kernel <<<NPIX / 1024, 256, 0, stream>>>(x, b_in, bits1);
    conv1_kernel<<<NPIX / 256, 256, 0, stream>>>(x, b2_, bits1, w1b, a1, xres, bits2);
    conv2_kernel<<<NPIX / 512, 256, 0, stream>>>(xres, bits2, w2b, a2, b3, s2, b4, out);
}